// Round 17
// baseline (231.333 us; speedup 1.0000x reference)
//
#include <hip/hip_runtime.h>

#define FDIM 100
#define SEQ 101
#define DIM 32
#define DEPTH 6
#define HEADS 8
#define DH 16
#define HIDN 100
#define FFH 128
#define FYH 1000
#define LN_EPS 1e-5f

typedef _Float16 f16;
typedef __attribute__((ext_vector_type(2))) __fp16 hf16x2;   // builtin cvt_pkrtz return type
typedef __attribute__((ext_vector_type(4))) _Float16 f16x4;
typedef __attribute__((ext_vector_type(8))) _Float16 f16x8;
typedef __attribute__((ext_vector_type(4))) float f32x4;

#define ZSTR 36   // 144B rows: 16B-aligned, tile accesses 2-way (free), LN conflict-free
#define YSTR 36

// d_ws layout (f16 element offsets).
#define WQ_OFF  0        // [l][h][q3][lane64][kk2][i4]   wqkv frags, x32 operand order (q==0 *QSCALE)
#define WO_OFF  73728    // [l][h][ct2][lane][i4]         wout^T frags (K=16)
#define F1_OFF  98304    // [l][jt8][lane][kk2][i4]       ff_w1^T frags, x32 order
#define F2_OFF  122880   // [l][ct2][jp4][lane][kk2][i4]  ff_w2^T frags, jt-paired x32 order
#define EW2_OFF 147456   // [f][j8 13][d32][p8]           mlp_w2 f16 pairs for v_dot2 (j>=100 -> 0)
#define EWB_OFF 480256   // [f][j4 25][8] = w1[j..j+3], b1[j..j+3]
#define WS_TOTAL 500256  // f16 elements = 1,000,512 B

#define QSCALE 0.36067376022224085f   // 0.25 * log2(e): softmax via raw v_exp_f32 (base-2)
#define GELU_A 2.30220842f            // 2*sqrt(2/pi)*log2(e)
#define GELU_B 0.10294323f            // GELU_A * 0.044715

// MFMA 16x16x16 f16 lane layout:
//  A-frag: lane l holds A[l15][4*l4+i]; B-frag: B[4*l4+i][l15]; D: lane reg r = D[4*l4+r][l15]
// 16x16x32: A/B = v8f16 (two K=16 frags concatenated; any consistent k-order cancels in the
// contraction), C/D layout identical to 16x16x16. Verified r12: absmax unchanged.
__device__ __forceinline__ f32x4 mfma16(f16x4 a, f16x4 b, f32x4 c) {
  return __builtin_amdgcn_mfma_f32_16x16x16f16(a, b, c, 0, 0, 0);
}
__device__ __forceinline__ f32x4 mfma32(f16x8 a, f16x8 b, f32x4 c) {
  return __builtin_amdgcn_mfma_f32_16x16x32_f16(a, b, c, 0, 0, 0);
}
__device__ __forceinline__ f16x4 pack4(f32x4 v) {   // v_cvt_pkrtz x2
  hf16x2 a = __builtin_amdgcn_cvt_pkrtz(v[0], v[1]);
  hf16x2 c = __builtin_amdgcn_cvt_pkrtz(v[2], v[3]);
  f16x4 r; r[0] = (f16)a[0]; r[1] = (f16)a[1]; r[2] = (f16)c[0]; r[3] = (f16)c[1];
  return r;
}
__device__ __forceinline__ f16x8 cat(f16x4 a, f16x4 b) {
  return __builtin_shufflevector(a, b, 0, 1, 2, 3, 4, 5, 6, 7);
}
__device__ __forceinline__ float ex2(float x) {     // raw v_exp_f32 (2^x)
  float r;
  asm("v_exp_f32 %0, %1" : "=v"(r) : "v"(x));
  return r;
}
__device__ __forceinline__ float gelu_fast(float x) {  // tanh-form gelu, exp2+rcp
  float w = ex2(x * fmaf(GELU_B, x * x, GELU_A));
  return x * w * __builtin_amdgcn_rcpf(w + 1.f);
}

// ---------------- prologue: weights -> f16 fragment layouts in d_ws ----------------
__global__ void prep_weights(const float* __restrict__ wqkv, const float* __restrict__ wout,
                             const float* __restrict__ ff_w1, const float* __restrict__ ff_w2,
                             const float* __restrict__ mlp_w1, const float* __restrict__ mlp_b1,
                             const float* __restrict__ mlp_w2, f16* __restrict__ ws) {
  for (int e = blockIdx.x * blockDim.x + threadIdx.x; e < WS_TOTAL; e += gridDim.x * blockDim.x) {
    float v;
    if (e < WO_OFF) {                       // WQ: [l][h][q][lane][kk][i]
      int o = e, i = o & 3, kk = (o >> 2) & 1, lane = (o >> 3) & 63, rest = o >> 9;
      int q = rest % 3, lh = rest / 3, h = lh & 7, l = lh >> 3;
      int k = kk * 16 + 4 * (lane >> 4) + i;
      v = wqkv[((size_t)l * 32 + k) * 384 + q * 128 + h * 16 + (lane & 15)];
      if (q == 0) v *= QSCALE;              // fold DH^-0.5 and log2(e)
    } else if (e < F1_OFF) {                // WO: [l][h][ct][lane][i]
      int o = e - WO_OFF, i = o & 3, lane = (o >> 2) & 63, ct = (o >> 8) & 1, lh = o >> 9;
      int h = lh & 7, l = lh >> 3;
      v = wout[((size_t)l * 128 + h * 16 + 4 * (lane >> 4) + i) * 32 + ct * 16 + (lane & 15)];
    } else if (e < F2_OFF) {                // F1: [l][jt][lane][kk][i]
      int o = e - F1_OFF, i = o & 3, kk = (o >> 2) & 1, lane = (o >> 3) & 63, lj = o >> 9;
      int jt = lj & 7, l = lj >> 3;
      v = ff_w1[((size_t)l * 32 + kk * 16 + 4 * (lane >> 4) + i) * 128 + jt * 16 + (lane & 15)];
    } else if (e < EW2_OFF) {               // F2: [l][ct][jp][lane][kk][i], jt = jp*2+kk
      int o = e - F2_OFF, i = o & 3, kk = (o >> 2) & 1, lane = (o >> 3) & 63;
      int jp = (o >> 9) & 3, lc = o >> 11, ct = lc & 1, l = lc >> 1;
      int jt = jp * 2 + kk;
      v = ff_w2[((size_t)l * 128 + jt * 16 + 4 * (lane >> 4) + i) * 32 + ct * 16 + (lane & 15)];
    } else if (e < EWB_OFF) {               // EW2 pairs: [f][j8][d][p]
      int o = e - EW2_OFF, p = o & 7, d = (o >> 3) & 31, j8 = (o >> 8) % 13, f = o / 3328;
      int j = j8 * 8 + p;
      v = (j < HIDN) ? mlp_w2[((size_t)f * HIDN + j) * DIM + d] : 0.f;
    } else {                                // EWB
      int o = e - EWB_OFF, i = o & 7, j4 = (o >> 3) % 25, f = o / 200;
      int j = j4 * 4 + (i & 3);
      v = (i < 4) ? mlp_w1[f * HIDN + j] : mlp_b1[f * HIDN + j];
    }
    ws[e] = (f16)v;
  }
}

// ---------------- fused transformer, one row per block ----------------
__global__ __launch_bounds__(256, 4) void saint_mfma(
    const float* __restrict__ x,
    const float* __restrict__ mlp_b2,
    const float* __restrict__ mask_emb,
    const float* __restrict__ cat_emb,
    const float* __restrict__ ln1_g, const float* __restrict__ ln1_b,
    const float* __restrict__ bout,
    const float* __restrict__ ln2_g, const float* __restrict__ ln2_b,
    const float* __restrict__ ff_b1, const float* __restrict__ ff_b2,
    const float* __restrict__ fy_w1, const float* __restrict__ fy_b1,
    const float* __restrict__ fy_w2, const float* __restrict__ fy_b2,
    const f16* __restrict__ ws,
    float* __restrict__ out)
{
  __shared__ float Z[SEQ][ZSTR];             // 14544 B fp32 residual stream
  __shared__ __align__(16) char U2[24448];   // Yh(8064)+KVf(16384) | embed hbuf [100][104]
  __shared__ float xrow[SEQ + 3];
  __shared__ float red[4];
  // total 39424 B -> 4 blocks/CU (zero dispatch tail)

  f16* const Yh   = (f16*)U2;                // [112][YSTR], rows 101..111 stay zero
  f16* const KVf  = (f16*)(U2 + 8064);       // [hs2][slot2][kv2][blk4][lane64][4] (8B-stride writes)
  f16* const hbuf = (f16*)U2;                // [100][104] (embed only)

  const int b = blockIdx.x;
  const int tid = threadIdx.x;
  const int lane = tid & 63;
  const int wid = tid >> 6;
  const int l15 = lane & 15;
  const int l4 = lane >> 4;

  const f32x4 zero4 = {0.f, 0.f, 0.f, 0.f};

  // ---------------- feature-embed MLP (shared h + v_dot2) ----------------
  {
    if (tid < SEQ) xrow[tid] = x[(size_t)b * SEQ + tid];
    __syncthreads();
    if (tid < DIM) {
      int ci = (int)xrow[0];
      Z[0][tid] = cat_emb[ci * DIM + tid];
    }
    // phase A: h[f][j] = relu(xv*w1+b1) once; j4-block per lane (no int div, b128 loads)
    const f16* ewb = ws + EWB_OFF;
    const int d = tid & 31, grp = tid >> 5;
    for (int f = grp; f < FDIM; f += 8) {
      if (d < 25) {
        float xv = xrow[1 + f];
        f16x8 wb = *(const f16x8*)(ewb + f * 200 + d * 8);   // w1[j..j+3], b1[j..j+3]
        f32x4 h;
        #pragma unroll
        for (int r = 0; r < 4; ++r)
          h[r] = fmaxf(fmaf(xv, (float)wb[r], (float)wb[4 + r]), 0.f);  // NaN*w -> fmax gives 0
        *(f16x4*)&hbuf[f * 104 + d * 4] = pack4(h);
      }
    }
    if (tid < FDIM) {   // zero pad cols 100..103
      f16x4 z; z[0] = (f16)0.f; z[1] = (f16)0.f; z[2] = (f16)0.f; z[3] = (f16)0.f;
      *(f16x4*)&hbuf[tid * 104 + 100] = z;
    }
    __syncthreads();
    // phase B: enc[f][d] = sum_j h[f][j] * w2[f][j][d] via fdot2
    const f16* ew2 = ws + EW2_OFF;
    for (int f = grp; f < FDIM; f += 8) {
      float xv = xrow[1 + f];
      float acc;
      if (xv != xv) {
        acc = mask_emb[(2 * f) * DIM + d];
      } else {
        float a0 = 0.f, a1 = 0.f;
        const f16* w2 = ew2 + f * 3328 + d * 8;
        const f16* hp = hbuf + f * 104;
        #pragma unroll 4
        for (int j8 = 0; j8 < 13; ++j8) {
          f16x8 hv = *(const f16x8*)(hp + j8 * 8);
          f16x8 wv = *(const f16x8*)(w2 + (size_t)j8 * 256);
          a0 = __builtin_amdgcn_fdot2(__builtin_shufflevector(hv, hv, 0, 1),
                                      __builtin_shufflevector(wv, wv, 0, 1), a0, false);
          a1 = __builtin_amdgcn_fdot2(__builtin_shufflevector(hv, hv, 2, 3),
                                      __builtin_shufflevector(wv, wv, 2, 3), a1, false);
          a0 = __builtin_amdgcn_fdot2(__builtin_shufflevector(hv, hv, 4, 5),
                                      __builtin_shufflevector(wv, wv, 4, 5), a0, false);
          a1 = __builtin_amdgcn_fdot2(__builtin_shufflevector(hv, hv, 6, 7),
                                      __builtin_shufflevector(wv, wv, 6, 7), a1, false);
        }
        acc = a0 + a1 + mlp_b2[f * DIM + d];
      }
      Z[1 + f][d] = acc;
    }
  }
  __syncthreads();
  // zero Yh pad rows (hbuf now dead); they stay zero through all layers
  for (int i = tid; i < 11 * YSTR; i += 256) Yh[101 * YSTR + i] = (f16)0.f;
  __syncthreads();

  const int k4 = (lane & 7) * 4;          // LN: column block
  const int rw = wid * 8 + (lane >> 3);   // LN: row within 32-row group

  #pragma unroll 1
  for (int l = 0; l < DEPTH; ++l) {
    // ---- LN1: Yh = f16(ln(Z)); Z = ln(Z) + bout ----
    {
      const f32x4 gv = *(const f32x4*)(ln1_g + l * DIM + k4);
      const f32x4 bv = *(const f32x4*)(ln1_b + l * DIM + k4);
      const f32x4 ov = *(const f32x4*)(bout + l * DIM + k4);
      #pragma unroll
      for (int it = 0; it < 4; ++it) {
        const int s = it * 32 + rw;
        if (s < SEQ) {
          f32x4 v = *(const f32x4*)&Z[s][k4];
          float m = v[0] + v[1] + v[2] + v[3];
          m += __shfl_xor(m, 1); m += __shfl_xor(m, 2); m += __shfl_xor(m, 4);
          m *= 0.03125f;
          f32x4 cv = {v[0] - m, v[1] - m, v[2] - m, v[3] - m};
          float vr = cv[0] * cv[0] + cv[1] * cv[1] + cv[2] * cv[2] + cv[3] * cv[3];
          vr += __shfl_xor(vr, 1); vr += __shfl_xor(vr, 2); vr += __shfl_xor(vr, 4);
          float rs = rsqrtf(vr * 0.03125f + LN_EPS);
          f32x4 ln, zo;
          #pragma unroll
          for (int r = 0; r < 4; ++r) {
            ln[r] = cv[r] * rs * gv[r] + bv[r];
            zo[r] = ln[r] + ov[r];
          }
          *(f16x4*)&Yh[s * YSTR + k4] = pack4(ln);
          *(f32x4*)&Z[s][k4] = zo;
        }
      }
    }
    __syncthreads();

    // ---- attention: head pairs; KV->LDS frags, Q in regs, in-reg softmax ----
    f32x4 zp[2][2];
    zp[0][0] = zero4; zp[0][1] = zero4; zp[1][0] = zero4; zp[1][1] = zero4;

    #pragma unroll 1
    for (int hp2 = 0; hp2 < 4; ++hp2) {
      // -- phase 1: QKV frags via x32 MFMA (1 issue each); Q stays in registers --
      f16x4 fq00, fq01, fq10, fq11;   // [hs][tt], wave-private (phase2 reads same tiles)
      {
        auto stage1 = [&](int h, int hsSlot, f16x4& fqa, f16x4& fqb) {
          const f16* pq = ws + WQ_OFF + (size_t)(l * 8 + h) * 1536 + lane * 8;
          const f16x8 aQ = *(const f16x8*)pq;
          const f16x8 aK = *(const f16x8*)(pq + 512);
          const f16x8 bV = *(const f16x8*)(pq + 1024);
          #pragma unroll
          for (int tt = 0; tt < 2; ++tt) {
            const int t = wid + 4 * tt;
            if (t < 7) {
              const int s = t * 16 + l15;
              f16x4 y0 = *(const f16x4*)&Yh[s * YSTR + 4 * l4];
              f16x4 y1 = *(const f16x4*)&Yh[s * YSTR + 16 + 4 * l4];
              f16x8 yv = cat(y0, y1);
              f32x4 dQ = mfma32(aQ, yv, zero4);   // Q^T frag
              f32x4 dK = mfma32(aK, yv, zero4);   // K^T frag
              f32x4 dV = mfma32(yv, bV, zero4);   // V frag
              if (tt == 0) fqa = pack4(dQ); else fqb = pack4(dQ);
              // 8B writes at 8B lane stride: conflict-free (was 16B stride = 4x conflict)
              *(f16x4*)(KVf + ((((hsSlot * 2 + (t & 1)) * 2 + 0) * 4 + (t >> 1)) * 64 + lane) * 4) = pack4(dK);
              *(f16x4*)(KVf + ((((hsSlot * 2 + (t & 1)) * 2 + 1) * 4 + (t >> 1)) * 64 + lane) * 4) = pack4(dV);
            }
          }
        };
        stage1(hp2 * 2 + 0, 0, fq00, fq01);
        stage1(hp2 * 2 + 1, 1, fq10, fq11);
      }
      __syncthreads();

      // -- phase 2: one head at a time (serialized for liveness); base-2 softmax; x32 AV --
      #pragma unroll 1
      for (int hs = 0; hs < 2; ++hs) {
        const int h = hp2 * 2 + hs;
        const f16* pw = ws + WO_OFF + (size_t)(l * 8 + h) * 512 + lane * 4;
        const f16x4 aW0 = *(const f16x4*)pw;
        const f16x4 aW1 = *(const f16x4*)(pw + 256);
        #pragma unroll
        for (int tt = 0; tt < 2; ++tt) {
          const int ns = wid + 4 * tt;
          if (ns < 7) {
            const f16x4 bQ = hs ? (tt ? fq11 : fq10) : (tt ? fq01 : fq00);
            f32x4 sv = zero4;
            f16x4 bP[7];
            #pragma unroll
            for (int jt2 = 0; jt2 < 3; ++jt2) {
              f16x4 klo = *(const f16x4*)(KVf + ((((hs * 2 + 0) * 2 + 0) * 4 + jt2) * 64 + lane) * 4);
              f16x4 khi = *(const f16x4*)(KVf + ((((hs * 2 + 1) * 2 + 0) * 4 + jt2) * 64 + lane) * 4);
              f32x4 L0 = mfma16(klo, bQ, zero4);
              f32x4 L1 = mfma16(khi, bQ, zero4);
              f32x4 e0, e1;
              #pragma unroll
              for (int r = 0; r < 4; ++r) { e0[r] = ex2(L0[r]); e1[r] = ex2(L1[r]); }
              sv += e0; sv += e1;
              bP[2 * jt2] = pack4(e0); bP[2 * jt2 + 1] = pack4(e1);
            }
            {
              f16x4 k6 = *(const f16x4*)(KVf + ((((hs * 2 + 0) * 2 + 0) * 4 + 3) * 64 + lane) * 4);
              f32x4 L6 = mfma16(k6, bQ, zero4);
              f32x4 e;
              #pragma unroll
              for (int r = 0; r < 4; ++r) e[r] = (4 * l4 + r > 4) ? 0.f : ex2(L6[r]);
              sv += e; bP[6] = pack4(e);
            }
            float sum = sv[0] + sv[1] + sv[2] + sv[3];
            sum += __shfl_xor(sum, 16);
            sum += __shfl_xor(sum, 32);
            const float inv = 1.f / sum;
            // AV via x32: V-frag pair (slot0, slot1) cat'd = v8f16 A-operand
            f32x4 Oa = zero4, Ob = zero4;
            { f16x4 vlo = *(const f16x4*)(KVf + ((((hs * 2 + 0) * 2 + 1) * 4 + 0) * 64 + lane) * 4);
              f16x4 vhi = *(const f16x4*)(KVf + ((((hs * 2 + 1) * 2 + 1) * 4 + 0) * 64 + lane) * 4);
              Oa = mfma32(cat(vlo, vhi), cat(bP[0], bP[1]), Oa); }
            { f16x4 vlo = *(const f16x4*)(KVf + ((((hs * 2 + 0) * 2 + 1) * 4 + 1) * 64 + lane) * 4);
              f16x4 vhi = *(const f16x4*)(KVf + ((((hs * 2 + 1) * 2 + 1) * 4 + 1) * 64 + lane) * 4);
              Ob = mfma32(cat(vlo, vhi), cat(bP[2], bP[3]), Ob); }
            { f16x4 vlo = *(const f16x4*)(KVf + ((((hs * 2 + 0) * 2 + 1) * 4 + 2) * 64 + lane) * 4);
              f16x4 vhi = *(const f16x4*)(KVf + ((((hs * 2 + 1) * 2 + 1) * 4 + 2) * 64 + lane) * 4);
              Oa = mfma32(cat(vlo, vhi), cat(bP[4], bP[5]), Oa); }
            { f16x4 v6 = *(const f16x4*)(KVf + ((((hs * 2 + 0) * 2 + 1) * 4 + 3) * 64 + lane) * 4);
              Ob = mfma16(v6, bP[6], Ob); }
            f32x4 ov;
            #pragma unroll
            for (int r = 0; r < 4; ++r) ov[r] = (Oa[r] + Ob[r]) * inv;
            f16x4 bO = pack4(ov);
            zp[0][tt] = mfma16(aW0, bO, zp[0][tt]);   // proj^T c-tile 0
            zp[1][tt] = mfma16(aW1, bO, zp[1][tt]);   // proj^T c-tile 1
          }
        }
      }
      __syncthreads();
    }

    // ---- attn residual: each wave adds zp into its own tiles (no atomics) ----
    #pragma unroll
    for (int tt = 0; tt < 2; ++tt) {
      const int ns = wid + 4 * tt;
      if (ns < 7) {
        const int s = ns * 16 + l15;
        if (s < SEQ) {
          f32x4 z0 = *(const f32x4*)&Z[s][4 * l4];
          f32x4 z1 = *(const f32x4*)&Z[s][16 + 4 * l4];
          z0 += zp[0][tt]; z1 += zp[1][tt];
          *(f32x4*)&Z[s][4 * l4] = z0;
          *(f32x4*)&Z[s][16 + 4 * l4] = z1;
        }
      }
    }
    __syncthreads();

    // ---- LN2 ----
    {
      const f32x4 gv = *(const f32x4*)(ln2_g + l * DIM + k4);
      const f32x4 bv = *(const f32x4*)(ln2_b + l * DIM + k4);
      const f32x4 ov = *(const f32x4*)(ff_b2 + l * DIM + k4);
      #pragma unroll
      for (int it = 0; it < 4; ++it) {
        const int s = it * 32 + rw;
        if (s < SEQ) {
          f32x4 v = *(const f32x4*)&Z[s][k4];
          float m = v[0] + v[1] + v[2] + v[3];
          m += __shfl_xor(m, 1); m += __shfl_xor(m, 2); m += __shfl_xor(m, 4);
          m *= 0.03125f;
          f32x4 cv = {v[0] - m, v[1] - m, v[2] - m, v[3] - m};
          float vr = cv[0] * cv[0] + cv[1] * cv[1] + cv[2] * cv[2] + cv[3] * cv[3];
          vr += __shfl_xor(vr, 1); vr += __shfl_xor(vr, 2); vr += __shfl_xor(vr, 4);
          float rs = rsqrtf(vr * 0.03125f + LN_EPS);
          f32x4 ln, zo;
          #pragma unroll
          for (int r = 0; r < 4; ++r) {
            ln[r] = cv[r] * rs * gv[r] + bv[r];
            zo[r] = ln[r] + ov[r];
          }
          *(f16x4*)&Yh[s * YSTR + k4] = pack4(ln);
          *(f32x4*)&Z[s][k4] = zo;
        }
      }
    }
    __syncthreads();

    // ---- FF via x32: FF1 one issue per jt; FF2 jt-paired; fast gelu ----
    {
      f32x4 facc[2][2];   // [ct][tt] accumulators, persist across halves
      facc[0][0] = zero4; facc[0][1] = zero4; facc[1][0] = zero4; facc[1][1] = zero4;
      #pragma unroll 1
      for (int half = 0; half < 2; ++half) {
        f16x8 a1[4], a2[2][2];
        const f16* p1 = ws + F1_OFF + (size_t)l * 4096 + (size_t)half * 2048 + lane * 8;
        const f16* p2 = ws + F2_OFF + (size_t)l * 4096 + (size_t)half * 1024 + lane * 8;
        #pragma unroll
        for (int q = 0; q < 4; ++q) a1[q] = *(const f16x8*)(p1 + q * 512);
        #pragma unroll
        for (int jp = 0; jp < 2; ++jp) {
          a2[0][jp] = *(const f16x8*)(p2 + jp * 512);
          a2[1][jp] = *(const f16x8*)(p2 + 2048 + jp * 512);
        }
        #pragma unroll
        for (int tt = 0; tt < 2; ++tt) {
          const int ns = wid + 4 * tt;
          if (ns < 7) {
            const int s = ns * 16 + l15;
            f16x4 y0 = *(const f16x4*)&Yh[s * YSTR + 4 * l4];
            f16x4 y1 = *(const f16x4*)&Yh[s * YSTR + 16 + 4 * l4];
            f16x8 yv = cat(y0, y1);
            #pragma unroll
            for (int q2 = 0; q2 < 2; ++q2) {
              const int jt0 = half * 4 + q2 * 2;
              f32x4 d0 = mfma32(a1[q2 * 2], yv, zero4);
              f32x4 d1 = mfma32(a1[q2 * 2 + 1], yv, zero4);
              const f32x4 bb0 = *(const f32x4*)(ff_b1 + l * FFH + jt0 * 16 + 4 * l4);
              const f32x4 bb1 = *(const f32x4*)(ff_b1 + l * FFH + (jt0 + 1) * 16 + 4 * l4);
              f32x4 g0, g1;
              #pragma unroll
              for (int r = 0; r < 4; ++r) {
                g0[r] = gelu_fast(d0[r] + bb0[r]);
                g1[r] = gelu_fast(d1[r] + bb1[r]);
              }
              f16x8 hv = cat(pack4(g0), pack4(g1));
              facc[0][tt] = mfma32(a2[0][q2], hv, facc[0][tt]);
              facc[1][tt] = mfma32(a2[1][q2], hv, facc[1][tt]);
            }
          }
        }
      }
      // residual write
      #pragma unroll
      for (int tt = 0; tt < 2; ++tt) {
        const int ns = wid + 4 * tt;
        if (ns < 7) {
          const int s = ns * 16 + l15;
          if (s < SEQ) {
            f32x4 z0 = *(const f32x4*)&Z[s][4 * l4];
            f32x4 z1 = *(const f32x4*)&Z[s][16 + 4 * l4];
            z0 += facc[0][tt]; z1 += facc[1][tt];
            *(f32x4*)&Z[s][4 * l4] = z0;
            *(f32x4*)&Z[s][16 + 4 * l4] = z1;
          }
        }
      }
    }
    __syncthreads();
  }

  // ---------------- final head ----------------
  {
    float part = 0.f;
    for (int j = tid; j < FYH; j += 256) {
      float acc = fy_b1[j];
      #pragma unroll
      for (int c = 0; c < DIM; ++c) acc = fmaf(Z[0][c], fy_w1[c * FYH + j], acc);
      part += fmaxf(acc, 0.f) * fy_w2[j];
    }
    #pragma unroll
    for (int off = 32; off; off >>= 1) part += __shfl_xor(part, off, 64);
    if (lane == 0) red[wid] = part;
    __syncthreads();
    if (tid == 0) out[b] = red[0] + red[1] + red[2] + red[3] + fy_b2[0];
  }
}

extern "C" void kernel_launch(void* const* d_in, const int* in_sizes, int n_in,
                              void* d_out, int out_size, void* d_ws, size_t ws_size,
                              hipStream_t stream) {
  (void)in_sizes; (void)n_in; (void)out_size; (void)ws_size;
  f16* ws = (f16*)d_ws;
  prep_weights<<<dim3(512), dim3(256), 0, stream>>>(
      (const float*)d_in[9],  (const float*)d_in[10],
      (const float*)d_in[14], (const float*)d_in[16],
      (const float*)d_in[1],  (const float*)d_in[2],  (const float*)d_in[3], ws);
  saint_mfma<<<dim3(1024), dim3(256), 0, stream>>>(
      (const float*)d_in[0],                          // x
      (const float*)d_in[4],                          // mlp_b2
      (const float*)d_in[5],  (const float*)d_in[6],  // mask_emb, cat_emb
      (const float*)d_in[7],  (const float*)d_in[8],  // ln1_g, ln1_b
      (const float*)d_in[11],                         // bout
      (const float*)d_in[12], (const float*)d_in[13], // ln2_g, ln2_b
      (const float*)d_in[15], (const float*)d_in[17], // ff_b1, ff_b2
      (const float*)d_in[18], (const float*)d_in[19], // fy_w1, fy_b1
      (const float*)d_in[20], (const float*)d_in[21], // fy_w2, fy_b2
      ws, (float*)d_out);
}

// Round 18
// 224.005 us; speedup vs baseline: 1.0327x; 1.0327x over previous
//
#include <hip/hip_runtime.h>

#define FDIM 100
#define SEQ 101
#define DIM 32
#define DEPTH 6
#define HEADS 8
#define DH 16
#define HIDN 100
#define FFH 128
#define FYH 1000
#define LN_EPS 1e-5f

typedef _Float16 f16;
typedef __attribute__((ext_vector_type(2))) __fp16 hf16x2;   // builtin cvt_pkrtz return type
typedef __attribute__((ext_vector_type(4))) _Float16 f16x4;
typedef __attribute__((ext_vector_type(8))) _Float16 f16x8;
typedef __attribute__((ext_vector_type(4))) float f32x4;

#define ZSTR 36   // 144B rows: 16B-aligned, tile accesses 2-way (free), LN conflict-free
#define YSTR 36

// d_ws layout (f16 element offsets).
#define WQ_OFF  0        // [l][h][q3][lane64][kk2][i4]   wqkv frags, x32 operand order (q==0 *QSCALE)
#define WO_OFF  73728    // [l][h][ct2][lane][i4]         wout^T frags (K=16)
#define F1_OFF  98304    // [l][jt8][lane][kk2][i4]       ff_w1^T frags, x32 order
#define F2_OFF  122880   // [l][ct2][jp4][lane][kk2][i4]  ff_w2^T frags, jt-paired x32 order
#define EW2_OFF 147456   // [f][j8 13][d32][p8]           mlp_w2 f16 pairs for v_dot2 (j>=100 -> 0)
#define EWB_OFF 480256   // [f][j4 25][8] = w1[j..j+3], b1[j..j+3]
#define WS_TOTAL 500256  // f16 elements = 1,000,512 B

#define QSCALE 0.36067376022224085f   // 0.25 * log2(e): softmax via raw v_exp_f32 (base-2)
#define GELU_A 2.30220842f            // 2*sqrt(2/pi)*log2(e)
#define GELU_B 0.10294323f            // GELU_A * 0.044715

// MFMA 16x16x16 f16 lane layout:
//  A-frag: lane l holds A[l15][4*l4+i]; B-frag: B[4*l4+i][l15]; D: lane reg r = D[4*l4+r][l15]
// 16x16x32: A/B = v8f16 (two K=16 frags concatenated; any consistent k-order cancels in the
// contraction), C/D layout identical to 16x16x16. Verified r12: absmax unchanged.
__device__ __forceinline__ f32x4 mfma16(f16x4 a, f16x4 b, f32x4 c) {
  return __builtin_amdgcn_mfma_f32_16x16x16f16(a, b, c, 0, 0, 0);
}
__device__ __forceinline__ f32x4 mfma32(f16x8 a, f16x8 b, f32x4 c) {
  return __builtin_amdgcn_mfma_f32_16x16x32_f16(a, b, c, 0, 0, 0);
}
__device__ __forceinline__ f16x4 pack4(f32x4 v) {   // v_cvt_pkrtz x2
  hf16x2 a = __builtin_amdgcn_cvt_pkrtz(v[0], v[1]);
  hf16x2 c = __builtin_amdgcn_cvt_pkrtz(v[2], v[3]);
  f16x4 r; r[0] = (f16)a[0]; r[1] = (f16)a[1]; r[2] = (f16)c[0]; r[3] = (f16)c[1];
  return r;
}
__device__ __forceinline__ f16x4 lo4(f16x8 v) { return __builtin_shufflevector(v, v, 0, 1, 2, 3); }
__device__ __forceinline__ f16x8 cat(f16x4 a, f16x4 b) {
  return __builtin_shufflevector(a, b, 0, 1, 2, 3, 4, 5, 6, 7);
}
__device__ __forceinline__ float ex2(float x) {     // raw v_exp_f32 (2^x)
  float r;
  asm("v_exp_f32 %0, %1" : "=v"(r) : "v"(x));
  return r;
}
__device__ __forceinline__ float gelu_fast(float x) {  // tanh-form gelu, exp2+rcp
  float w = ex2(x * fmaf(GELU_B, x * x, GELU_A));
  return x * w * __builtin_amdgcn_rcpf(w + 1.f);
}

// ---------------- prologue: weights -> f16 fragment layouts in d_ws ----------------
__global__ void prep_weights(const float* __restrict__ wqkv, const float* __restrict__ wout,
                             const float* __restrict__ ff_w1, const float* __restrict__ ff_w2,
                             const float* __restrict__ mlp_w1, const float* __restrict__ mlp_b1,
                             const float* __restrict__ mlp_w2, f16* __restrict__ ws) {
  for (int e = blockIdx.x * blockDim.x + threadIdx.x; e < WS_TOTAL; e += gridDim.x * blockDim.x) {
    float v;
    if (e < WO_OFF) {                       // WQ: [l][h][q][lane][kk][i]
      int o = e, i = o & 3, kk = (o >> 2) & 1, lane = (o >> 3) & 63, rest = o >> 9;
      int q = rest % 3, lh = rest / 3, h = lh & 7, l = lh >> 3;
      int k = kk * 16 + 4 * (lane >> 4) + i;
      v = wqkv[((size_t)l * 32 + k) * 384 + q * 128 + h * 16 + (lane & 15)];
      if (q == 0) v *= QSCALE;              // fold DH^-0.5 and log2(e)
    } else if (e < F1_OFF) {                // WO: [l][h][ct][lane][i]
      int o = e - WO_OFF, i = o & 3, lane = (o >> 2) & 63, ct = (o >> 8) & 1, lh = o >> 9;
      int h = lh & 7, l = lh >> 3;
      v = wout[((size_t)l * 128 + h * 16 + 4 * (lane >> 4) + i) * 32 + ct * 16 + (lane & 15)];
    } else if (e < F2_OFF) {                // F1: [l][jt][lane][kk][i]
      int o = e - F1_OFF, i = o & 3, kk = (o >> 2) & 1, lane = (o >> 3) & 63, lj = o >> 9;
      int jt = lj & 7, l = lj >> 3;
      v = ff_w1[((size_t)l * 32 + kk * 16 + 4 * (lane >> 4) + i) * 128 + jt * 16 + (lane & 15)];
    } else if (e < EW2_OFF) {               // F2: [l][ct][jp][lane][kk][i], jt = jp*2+kk
      int o = e - F2_OFF, i = o & 3, kk = (o >> 2) & 1, lane = (o >> 3) & 63;
      int jp = (o >> 9) & 3, lc = o >> 11, ct = lc & 1, l = lc >> 1;
      int jt = jp * 2 + kk;
      v = ff_w2[((size_t)l * 128 + jt * 16 + 4 * (lane >> 4) + i) * 32 + ct * 16 + (lane & 15)];
    } else if (e < EWB_OFF) {               // EW2 pairs: [f][j8][d][p]
      int o = e - EW2_OFF, p = o & 7, d = (o >> 3) & 31, j8 = (o >> 8) % 13, f = o / 3328;
      int j = j8 * 8 + p;
      v = (j < HIDN) ? mlp_w2[((size_t)f * HIDN + j) * DIM + d] : 0.f;
    } else {                                // EWB
      int o = e - EWB_OFF, i = o & 7, j4 = (o >> 3) % 25, f = o / 200;
      int j = j4 * 4 + (i & 3);
      v = (i < 4) ? mlp_w1[f * HIDN + j] : mlp_b1[f * HIDN + j];
    }
    ws[e] = (f16)v;
  }
}

// ---------------- fused transformer, one row per block ----------------
__global__ __launch_bounds__(256, 4) void saint_mfma(
    const float* __restrict__ x,
    const float* __restrict__ mlp_b2,
    const float* __restrict__ mask_emb,
    const float* __restrict__ cat_emb,
    const float* __restrict__ ln1_g, const float* __restrict__ ln1_b,
    const float* __restrict__ bout,
    const float* __restrict__ ln2_g, const float* __restrict__ ln2_b,
    const float* __restrict__ ff_b1, const float* __restrict__ ff_b2,
    const float* __restrict__ fy_w1, const float* __restrict__ fy_b1,
    const float* __restrict__ fy_w2, const float* __restrict__ fy_b2,
    const f16* __restrict__ ws,
    float* __restrict__ out)
{
  __shared__ float Z[SEQ][ZSTR];             // 14544 B fp32 residual stream
  __shared__ __align__(16) char U2[24448];   // Yh(8064)+KVf(16384) | embed hbuf [100][104]
  __shared__ float xrow[SEQ + 3];
  __shared__ float red[4];
  // total 39424 B -> 4 blocks/CU (zero dispatch tail)

  f16* const Yh   = (f16*)U2;                // [112][YSTR], rows 101..111 stay zero
  f16* const KVf  = (f16*)(U2 + 8064);       // [hs2][kv2][jt2 4][lane64][8]
  f16* const hbuf = (f16*)U2;                // [100][104] (embed only)

  const int b = blockIdx.x;
  const int tid = threadIdx.x;
  const int lane = tid & 63;
  const int wid = tid >> 6;
  const int l15 = lane & 15;
  const int l4 = lane >> 4;

  const f32x4 zero4 = {0.f, 0.f, 0.f, 0.f};

  // ---------------- feature-embed MLP (shared h + v_dot2) ----------------
  {
    if (tid < SEQ) xrow[tid] = x[(size_t)b * SEQ + tid];
    __syncthreads();
    if (tid < DIM) {
      int ci = (int)xrow[0];
      Z[0][tid] = cat_emb[ci * DIM + tid];
    }
    // phase A: h[f][j] = relu(xv*w1+b1) once; j4-block per lane (no int div, b128 loads)
    const f16* ewb = ws + EWB_OFF;
    const int d = tid & 31, grp = tid >> 5;
    for (int f = grp; f < FDIM; f += 8) {
      if (d < 25) {
        float xv = xrow[1 + f];
        f16x8 wb = *(const f16x8*)(ewb + f * 200 + d * 8);   // w1[j..j+3], b1[j..j+3]
        f32x4 h;
        #pragma unroll
        for (int r = 0; r < 4; ++r)
          h[r] = fmaxf(fmaf(xv, (float)wb[r], (float)wb[4 + r]), 0.f);  // NaN*w -> fmax gives 0
        *(f16x4*)&hbuf[f * 104 + d * 4] = pack4(h);
      }
    }
    if (tid < FDIM) {   // zero pad cols 100..103
      f16x4 z; z[0] = (f16)0.f; z[1] = (f16)0.f; z[2] = (f16)0.f; z[3] = (f16)0.f;
      *(f16x4*)&hbuf[tid * 104 + 100] = z;
    }
    __syncthreads();
    // phase B: enc[f][d] = sum_j h[f][j] * w2[f][j][d] via fdot2
    const f16* ew2 = ws + EW2_OFF;
    for (int f = grp; f < FDIM; f += 8) {
      float xv = xrow[1 + f];
      float acc;
      if (xv != xv) {
        acc = mask_emb[(2 * f) * DIM + d];
      } else {
        float a0 = 0.f, a1 = 0.f;
        const f16* w2 = ew2 + f * 3328 + d * 8;
        const f16* hp = hbuf + f * 104;
        #pragma unroll 4
        for (int j8 = 0; j8 < 13; ++j8) {
          f16x8 hv = *(const f16x8*)(hp + j8 * 8);
          f16x8 wv = *(const f16x8*)(w2 + (size_t)j8 * 256);
          a0 = __builtin_amdgcn_fdot2(__builtin_shufflevector(hv, hv, 0, 1),
                                      __builtin_shufflevector(wv, wv, 0, 1), a0, false);
          a1 = __builtin_amdgcn_fdot2(__builtin_shufflevector(hv, hv, 2, 3),
                                      __builtin_shufflevector(wv, wv, 2, 3), a1, false);
          a0 = __builtin_amdgcn_fdot2(__builtin_shufflevector(hv, hv, 4, 5),
                                      __builtin_shufflevector(wv, wv, 4, 5), a0, false);
          a1 = __builtin_amdgcn_fdot2(__builtin_shufflevector(hv, hv, 6, 7),
                                      __builtin_shufflevector(wv, wv, 6, 7), a1, false);
        }
        acc = a0 + a1 + mlp_b2[f * DIM + d];
      }
      Z[1 + f][d] = acc;
    }
  }
  __syncthreads();
  // zero Yh pad rows (hbuf now dead); they stay zero through all layers
  for (int i = tid; i < 11 * YSTR; i += 256) Yh[101 * YSTR + i] = (f16)0.f;
  __syncthreads();

  const int k4 = (lane & 7) * 4;          // LN: column block
  const int rw = wid * 8 + (lane >> 3);   // LN: row within 32-row group

  #pragma unroll 1
  for (int l = 0; l < DEPTH; ++l) {
    // ---- LN1: Yh = f16(ln(Z)); Z = ln(Z) + bout ----
    {
      const f32x4 gv = *(const f32x4*)(ln1_g + l * DIM + k4);
      const f32x4 bv = *(const f32x4*)(ln1_b + l * DIM + k4);
      const f32x4 ov = *(const f32x4*)(bout + l * DIM + k4);
      #pragma unroll
      for (int it = 0; it < 4; ++it) {
        const int s = it * 32 + rw;
        if (s < SEQ) {
          f32x4 v = *(const f32x4*)&Z[s][k4];
          float m = v[0] + v[1] + v[2] + v[3];
          m += __shfl_xor(m, 1); m += __shfl_xor(m, 2); m += __shfl_xor(m, 4);
          m *= 0.03125f;
          f32x4 cv = {v[0] - m, v[1] - m, v[2] - m, v[3] - m};
          float vr = cv[0] * cv[0] + cv[1] * cv[1] + cv[2] * cv[2] + cv[3] * cv[3];
          vr += __shfl_xor(vr, 1); vr += __shfl_xor(vr, 2); vr += __shfl_xor(vr, 4);
          float rs = rsqrtf(vr * 0.03125f + LN_EPS);
          f32x4 ln, zo;
          #pragma unroll
          for (int r = 0; r < 4; ++r) {
            ln[r] = cv[r] * rs * gv[r] + bv[r];
            zo[r] = ln[r] + ov[r];
          }
          *(f16x4*)&Yh[s * YSTR + k4] = pack4(ln);
          *(f32x4*)&Z[s][k4] = zo;
        }
      }
    }
    __syncthreads();

    // ---- attention: head pairs; KV->LDS frags, Q in regs, in-reg softmax ----
    f32x4 zp[2][2];
    zp[0][0] = zero4; zp[0][1] = zero4; zp[1][0] = zero4; zp[1][1] = zero4;

    #pragma unroll 1
    for (int hp2 = 0; hp2 < 4; ++hp2) {
      // -- phase 1: QKV frags via x32 MFMA (1 issue each); Q stays in registers --
      f16x4 fq00, fq01, fq10, fq11;   // [hs][tt], wave-private (phase2 reads same tiles)
      {
        auto stage1 = [&](int h, int hsSlot, f16x4& fqa, f16x4& fqb) {
          const f16* pq = ws + WQ_OFF + (size_t)(l * 8 + h) * 1536 + lane * 8;
          const f16x8 aQ = *(const f16x8*)pq;
          const f16x8 aK = *(const f16x8*)(pq + 512);
          const f16x8 bV = *(const f16x8*)(pq + 1024);
          #pragma unroll
          for (int tt = 0; tt < 2; ++tt) {
            const int t = wid + 4 * tt;
            if (t < 7) {
              const int s = t * 16 + l15;
              f16x4 y0 = *(const f16x4*)&Yh[s * YSTR + 4 * l4];
              f16x4 y1 = *(const f16x4*)&Yh[s * YSTR + 16 + 4 * l4];
              f16x8 yv = cat(y0, y1);
              f32x4 dQ = mfma32(aQ, yv, zero4);   // Q^T frag
              f32x4 dK = mfma32(aK, yv, zero4);   // K^T frag
              f32x4 dV = mfma32(yv, bV, zero4);   // V frag
              if (tt == 0) fqa = pack4(dQ); else fqb = pack4(dQ);
              *(f16x4*)(KVf + (((hsSlot * 2 + 0) * 4 + (t >> 1)) * 64 + lane) * 8 + (t & 1) * 4) = pack4(dK);
              *(f16x4*)(KVf + (((hsSlot * 2 + 1) * 4 + (t >> 1)) * 64 + lane) * 8 + (t & 1) * 4) = pack4(dV);
            }
          }
        };
        stage1(hp2 * 2 + 0, 0, fq00, fq01);
        stage1(hp2 * 2 + 1, 1, fq10, fq11);
      }
      __syncthreads();

      // -- phase 2: one head at a time (serialized for liveness); base-2 softmax; x32 AV --
      #pragma unroll 1
      for (int hs = 0; hs < 2; ++hs) {
        const int h = hp2 * 2 + hs;
        const f16* pw = ws + WO_OFF + (size_t)(l * 8 + h) * 512 + lane * 4;
        const f16x4 aW0 = *(const f16x4*)pw;
        const f16x4 aW1 = *(const f16x4*)(pw + 256);
        #pragma unroll
        for (int tt = 0; tt < 2; ++tt) {
          const int ns = wid + 4 * tt;
          if (ns < 7) {
            const f16x4 bQ = hs ? (tt ? fq11 : fq10) : (tt ? fq01 : fq00);
            f32x4 sv = zero4;
            f16x4 bP[7];
            #pragma unroll
            for (int jt2 = 0; jt2 < 3; ++jt2) {
              f16x8 kp = *(const f16x8*)(KVf + (((hs * 2 + 0) * 4 + jt2) * 64 + lane) * 8);
              f32x4 L0 = mfma16(lo4(kp), bQ, zero4);
              f32x4 L1 = mfma16(__builtin_shufflevector(kp, kp, 4, 5, 6, 7), bQ, zero4);
              f32x4 e0, e1;
              #pragma unroll
              for (int r = 0; r < 4; ++r) { e0[r] = ex2(L0[r]); e1[r] = ex2(L1[r]); }
              sv += e0; sv += e1;
              bP[2 * jt2] = pack4(e0); bP[2 * jt2 + 1] = pack4(e1);
            }
            {
              f16x4 k6 = *(const f16x4*)(KVf + (((hs * 2 + 0) * 4 + 3) * 64 + lane) * 8);
              f32x4 L6 = mfma16(k6, bQ, zero4);
              f32x4 e;
              #pragma unroll
              for (int r = 0; r < 4; ++r) e[r] = (4 * l4 + r > 4) ? 0.f : ex2(L6[r]);
              sv += e; bP[6] = pack4(e);
            }
            float sum = sv[0] + sv[1] + sv[2] + sv[3];
            sum += __shfl_xor(sum, 16);
            sum += __shfl_xor(sum, 32);
            const float inv = 1.f / sum;
            // AV via x32: vp (pair of V-frags) is already the v8f16 A-operand
            f32x4 Oa = zero4, Ob = zero4;
            { f16x8 vp = *(const f16x8*)(KVf + (((hs * 2 + 1) * 4 + 0) * 64 + lane) * 8);
              Oa = mfma32(vp, cat(bP[0], bP[1]), Oa); }
            { f16x8 vp = *(const f16x8*)(KVf + (((hs * 2 + 1) * 4 + 1) * 64 + lane) * 8);
              Ob = mfma32(vp, cat(bP[2], bP[3]), Ob); }
            { f16x8 vp = *(const f16x8*)(KVf + (((hs * 2 + 1) * 4 + 2) * 64 + lane) * 8);
              Oa = mfma32(vp, cat(bP[4], bP[5]), Oa); }
            { f16x4 v6 = *(const f16x4*)(KVf + (((hs * 2 + 1) * 4 + 3) * 64 + lane) * 8);
              Ob = mfma16(v6, bP[6], Ob); }
            f32x4 ov;
            #pragma unroll
            for (int r = 0; r < 4; ++r) ov[r] = (Oa[r] + Ob[r]) * inv;
            f16x4 bO = pack4(ov);
            zp[0][tt] = mfma16(aW0, bO, zp[0][tt]);   // proj^T c-tile 0
            zp[1][tt] = mfma16(aW1, bO, zp[1][tt]);   // proj^T c-tile 1
          }
        }
      }
      __syncthreads();
    }

    // ---- attn residual: each wave adds zp into its own tiles (no atomics) ----
    #pragma unroll
    for (int tt = 0; tt < 2; ++tt) {
      const int ns = wid + 4 * tt;
      if (ns < 7) {
        const int s = ns * 16 + l15;
        if (s < SEQ) {
          f32x4 z0 = *(const f32x4*)&Z[s][4 * l4];
          f32x4 z1 = *(const f32x4*)&Z[s][16 + 4 * l4];
          z0 += zp[0][tt]; z1 += zp[1][tt];
          *(f32x4*)&Z[s][4 * l4] = z0;
          *(f32x4*)&Z[s][16 + 4 * l4] = z1;
        }
      }
    }
    __syncthreads();

    // ---- LN2 ----
    {
      const f32x4 gv = *(const f32x4*)(ln2_g + l * DIM + k4);
      const f32x4 bv = *(const f32x4*)(ln2_b + l * DIM + k4);
      const f32x4 ov = *(const f32x4*)(ff_b2 + l * DIM + k4);
      #pragma unroll
      for (int it = 0; it < 4; ++it) {
        const int s = it * 32 + rw;
        if (s < SEQ) {
          f32x4 v = *(const f32x4*)&Z[s][k4];
          float m = v[0] + v[1] + v[2] + v[3];
          m += __shfl_xor(m, 1); m += __shfl_xor(m, 2); m += __shfl_xor(m, 4);
          m *= 0.03125f;
          f32x4 cv = {v[0] - m, v[1] - m, v[2] - m, v[3] - m};
          float vr = cv[0] * cv[0] + cv[1] * cv[1] + cv[2] * cv[2] + cv[3] * cv[3];
          vr += __shfl_xor(vr, 1); vr += __shfl_xor(vr, 2); vr += __shfl_xor(vr, 4);
          float rs = rsqrtf(vr * 0.03125f + LN_EPS);
          f32x4 ln, zo;
          #pragma unroll
          for (int r = 0; r < 4; ++r) {
            ln[r] = cv[r] * rs * gv[r] + bv[r];
            zo[r] = ln[r] + ov[r];
          }
          *(f16x4*)&Yh[s * YSTR + k4] = pack4(ln);
          *(f32x4*)&Z[s][k4] = zo;
        }
      }
    }
    __syncthreads();

    // ---- FF via x32: FF1 one issue per jt; FF2 jt-paired; fast gelu ----
    {
      f32x4 facc[2][2];   // [ct][tt] accumulators, persist across halves
      facc[0][0] = zero4; facc[0][1] = zero4; facc[1][0] = zero4; facc[1][1] = zero4;
      #pragma unroll 1
      for (int half = 0; half < 2; ++half) {
        f16x8 a1[4], a2[2][2];
        const f16* p1 = ws + F1_OFF + (size_t)l * 4096 + (size_t)half * 2048 + lane * 8;
        const f16* p2 = ws + F2_OFF + (size_t)l * 4096 + (size_t)half * 1024 + lane * 8;
        #pragma unroll
        for (int q = 0; q < 4; ++q) a1[q] = *(const f16x8*)(p1 + q * 512);
        #pragma unroll
        for (int jp = 0; jp < 2; ++jp) {
          a2[0][jp] = *(const f16x8*)(p2 + jp * 512);
          a2[1][jp] = *(const f16x8*)(p2 + 2048 + jp * 512);
        }
        #pragma unroll
        for (int tt = 0; tt < 2; ++tt) {
          const int ns = wid + 4 * tt;
          if (ns < 7) {
            const int s = ns * 16 + l15;
            f16x4 y0 = *(const f16x4*)&Yh[s * YSTR + 4 * l4];
            f16x4 y1 = *(const f16x4*)&Yh[s * YSTR + 16 + 4 * l4];
            f16x8 yv = cat(y0, y1);
            #pragma unroll
            for (int q2 = 0; q2 < 2; ++q2) {
              const int jt0 = half * 4 + q2 * 2;
              f32x4 d0 = mfma32(a1[q2 * 2], yv, zero4);
              f32x4 d1 = mfma32(a1[q2 * 2 + 1], yv, zero4);
              const f32x4 bb0 = *(const f32x4*)(ff_b1 + l * FFH + jt0 * 16 + 4 * l4);
              const f32x4 bb1 = *(const f32x4*)(ff_b1 + l * FFH + (jt0 + 1) * 16 + 4 * l4);
              f32x4 g0, g1;
              #pragma unroll
              for (int r = 0; r < 4; ++r) {
                g0[r] = gelu_fast(d0[r] + bb0[r]);
                g1[r] = gelu_fast(d1[r] + bb1[r]);
              }
              f16x8 hv = cat(pack4(g0), pack4(g1));
              facc[0][tt] = mfma32(a2[0][q2], hv, facc[0][tt]);
              facc[1][tt] = mfma32(a2[1][q2], hv, facc[1][tt]);
            }
          }
        }
      }
      // residual write
      #pragma unroll
      for (int tt = 0; tt < 2; ++tt) {
        const int ns = wid + 4 * tt;
        if (ns < 7) {
          const int s = ns * 16 + l15;
          if (s < SEQ) {
            f32x4 z0 = *(const f32x4*)&Z[s][4 * l4];
            f32x4 z1 = *(const f32x4*)&Z[s][16 + 4 * l4];
            z0 += facc[0][tt]; z1 += facc[1][tt];
            *(f32x4*)&Z[s][4 * l4] = z0;
            *(f32x4*)&Z[s][16 + 4 * l4] = z1;
          }
        }
      }
    }
    __syncthreads();
  }

  // ---------------- final head ----------------
  {
    float part = 0.f;
    for (int j = tid; j < FYH; j += 256) {
      float acc = fy_b1[j];
      #pragma unroll
      for (int c = 0; c < DIM; ++c) acc = fmaf(Z[0][c], fy_w1[c * FYH + j], acc);
      part += fmaxf(acc, 0.f) * fy_w2[j];
    }
    #pragma unroll
    for (int off = 32; off; off >>= 1) part += __shfl_xor(part, off, 64);
    if (lane == 0) red[wid] = part;
    __syncthreads();
    if (tid == 0) out[b] = red[0] + red[1] + red[2] + red[3] + fy_b2[0];
  }
}

extern "C" void kernel_launch(void* const* d_in, const int* in_sizes, int n_in,
                              void* d_out, int out_size, void* d_ws, size_t ws_size,
                              hipStream_t stream) {
  (void)in_sizes; (void)n_in; (void)out_size; (void)ws_size;
  f16* ws = (f16*)d_ws;
  prep_weights<<<dim3(512), dim3(256), 0, stream>>>(
      (const float*)d_in[9],  (const float*)d_in[10],
      (const float*)d_in[14], (const float*)d_in[16],
      (const float*)d_in[1],  (const float*)d_in[2],  (const float*)d_in[3], ws);
  saint_mfma<<<dim3(1024), dim3(256), 0, stream>>>(
      (const float*)d_in[0],                          // x
      (const float*)d_in[4],                          // mlp_b2
      (const float*)d_in[5],  (const float*)d_in[6],  // mask_emb, cat_emb
      (const float*)d_in[7],  (const float*)d_in[8],  // ln1_g, ln1_b
      (const float*)d_in[11],                         // bout
      (const float*)d_in[12], (const float*)d_in[13], // ln2_g, ln2_b
      (const float*)d_in[15], (const float*)d_in[17], // ff_b1, ff_b2
      (const float*)d_in[18], (const float*)d_in[19], // fy_w1, fy_b1
      (const float*)d_in[20], (const float*)d_in[21], // fy_w2, fy_b2
      ws, (float*)d_out);
}